// Round 2
// baseline (3965.931 us; speedup 1.0000x reference)
//
#include <hip/hip_runtime.h>
#include <cstdint>
#include <cstddef>

// ----------------------------------------------------------------------------
// DCGAN-style generator. R2: bf16-storage pipeline, ~129MB workspace
// (R1 crashed: fp32 layout needed 471MB of d_ws -> ws overrun fault).
// Storage bf16, all arithmetic fp32. conv3 chunked over output channels (4x32)
// with conv4 accumulating into d_out so only one 32-ch slice of y3 is live.
// Workspace layout (bytes):
//   y2   @ 0          2048*256*64*2  = 64MB  (bf16, pre-BN then in-place act)
//   y1   @ 67108864   2048*512*16*2  = 32MB  (bf16)
//   y3c  @ 100663296  2048*32*256*2  = 32MB  (bf16, one conv3 chunk)
//   vals @ 134217728  2048*50*4
//   idxs @ 134627328  2048*50*4
//   sp   @ 135036928  512*8*4
//   sqp  @ 135053312  512*8*4
//   ac   @ 135069696  512*4
//   bc   @ 135071744  512*4
// Total ~135.1MB.
// ----------------------------------------------------------------------------

typedef unsigned short u16;
typedef unsigned int u32;

static __device__ __forceinline__ float bf2f(u16 u) {
  union { u32 i; float f; } v; v.i = ((u32)u) << 16; return v.f;
}
static __device__ __forceinline__ u16 f2bf(float f) {  // round-to-nearest-even
  union { float f; u32 i; } v; v.f = f;
  const u32 r = v.i + 0x7fffu + ((v.i >> 16) & 1u);
  return (u16)(r >> 16);
}

// ---------------- top-k(50) + log/clamp/shift -> sparse (val,idx) -----------
__global__ __launch_bounds__(256) void topk_kernel(const float* __restrict__ x,
                                                   float* __restrict__ vals,
                                                   int* __restrict__ idxs) {
  const int b = blockIdx.x;
  const int t = threadIdx.x;
  __shared__ float sv[1024];
  __shared__ float redv[4];
  __shared__ int redi[4];
  __shared__ float tv[50];
  __shared__ int ti[50];
  __shared__ float sshift;
  for (int i = t; i < 1000; i += 256) sv[i] = x[(size_t)b * 1000 + i];
  for (int i = 1000 + t; i < 1024; i += 256) sv[i] = -INFINITY;
  __syncthreads();
  for (int k = 0; k < 50; ++k) {
    float bv = -INFINITY;
    int bi = 0x7fffffff;
    #pragma unroll
    for (int s = 0; s < 4; ++s) {
      const int i = t + s * 256;
      const float v = sv[i];
      if (v > bv) { bv = v; bi = i; }   // ascending i -> strict > keeps lowest idx
    }
    for (int off = 32; off > 0; off >>= 1) {
      const float ov = __shfl_down(bv, off);
      const int oi = __shfl_down(bi, off);
      if (ov > bv || (ov == bv && oi < bi)) { bv = ov; bi = oi; }
    }
    if ((t & 63) == 0) { redv[t >> 6] = bv; redi[t >> 6] = bi; }
    __syncthreads();
    if (t == 0) {
      for (int w = 1; w < 4; ++w)
        if (redv[w] > bv || (redv[w] == bv && redi[w] < bi)) { bv = redv[w]; bi = redi[w]; }
      tv[k] = bv;
      ti[k] = bi;
      sv[bi] = -INFINITY;
    }
    __syncthreads();
  }
  if (t < 50) tv[t] = fmaxf(logf(tv[t]), -1000.0f) + 50.0f;
  __syncthreads();
  if (t == 0) {
    float mn = tv[0];
    for (int k = 1; k < 50; ++k) mn = fminf(mn, tv[k]);
    sshift = fmaxf(-mn, 0.0f);
  }
  __syncthreads();
  if (t < 50) {
    vals[b * 50 + t] = tv[t] + sshift;
    idxs[b * 50 + t] = ti[t];
  }
}

// ---------------- conv1: sparse (50 nnz) x w1[1000][512*16] -> bf16 ---------
__global__ __launch_bounds__(256) void conv1_kernel(const float* __restrict__ vals,
                                                    const int* __restrict__ idxs,
                                                    const float* __restrict__ w1,
                                                    const float* __restrict__ b1,
                                                    u16* __restrict__ y1) {
  const int b = blockIdx.y;
  const int t = threadIdx.x;
  __shared__ float sval[50];
  __shared__ int sidx[50];
  if (t < 50) { sval[t] = vals[b * 50 + t]; sidx[t] = idxs[b * 50 + t]; }
  __syncthreads();
  const int n0 = blockIdx.x * 1024 + t * 4;
  float4 acc = make_float4(0.f, 0.f, 0.f, 0.f);
  #pragma unroll 5
  for (int j = 0; j < 50; ++j) {
    const float v = sval[j];
    const float4 w = *reinterpret_cast<const float4*>(w1 + (size_t)sidx[j] * 8192 + n0);
    acc.x = fmaf(v, w.x, acc.x);
    acc.y = fmaf(v, w.y, acc.y);
    acc.z = fmaf(v, w.z, acc.z);
    acc.w = fmaf(v, w.w, acc.w);
  }
  const float bias = b1[n0 >> 4];  // channel = n/16
  ushort4 o;
  o.x = f2bf(acc.x + bias);
  o.y = f2bf(acc.y + bias);
  o.z = f2bf(acc.z + bias);
  o.w = f2bf(acc.w + bias);
  *reinterpret_cast<ushort4*>(y1 + (size_t)b * 8192 + n0) = o;
}

// ---------------- BN batch-stats on bf16 tensor (2-stage, deterministic) ----
// y layout [2048][Cs][S], S = 1<<log2S. One block per (channel, split).
__global__ __launch_bounds__(256) void bnstats_part_kernel(const u16* __restrict__ y,
                                                           float* __restrict__ sp,
                                                           float* __restrict__ sqp,
                                                           int Cs, int log2S) {
  const int c = blockIdx.x;
  const int split = blockIdx.y;
  const int t = threadIdx.x;
  const int S = 1 << log2S;
  const long long NS = 2048LL << log2S;
  const long long per = NS >> 3;
  const long long e0 = (long long)split * per;
  float s = 0.f, s2 = 0.f;
  for (long long e = e0 + (long long)t * 8; e < e0 + per; e += 2048) {
    const long long n = e >> log2S;
    const int p = (int)(e & (S - 1));
    const uint4 raw = *reinterpret_cast<const uint4*>(y + ((n * Cs + c) << log2S) + p);
    const u32 wq[4] = {raw.x, raw.y, raw.z, raw.w};
    #pragma unroll
    for (int q = 0; q < 4; ++q) {
      const float a = bf2f((u16)(wq[q] & 0xffffu));
      const float bb_ = bf2f((u16)(wq[q] >> 16));
      s += a + bb_;
      s2 = fmaf(a, a, s2);
      s2 = fmaf(bb_, bb_, s2);
    }
  }
  for (int off = 32; off > 0; off >>= 1) {
    s += __shfl_down(s, off);
    s2 += __shfl_down(s2, off);
  }
  __shared__ float rs[4], rq[4];
  if ((t & 63) == 0) { rs[t >> 6] = s; rq[t >> 6] = s2; }
  __syncthreads();
  if (t == 0) {
    sp[c * 8 + split] = rs[0] + rs[1] + rs[2] + rs[3];
    sqp[c * 8 + split] = rq[0] + rq[1] + rq[2] + rq[3];
  }
}

__global__ __launch_bounds__(256) void bnfinalize_kernel(const float* __restrict__ sp,
                                                         const float* __restrict__ sqp,
                                                         const float* __restrict__ g,
                                                         const float* __restrict__ be,
                                                         float* __restrict__ a,
                                                         float* __restrict__ bb,
                                                         int C, int log2S) {
  const int c = blockIdx.x * 256 + threadIdx.x;
  if (c >= C) return;
  float s = 0.f, s2 = 0.f;
  for (int k = 0; k < 8; ++k) { s += sp[c * 8 + k]; s2 += sqp[c * 8 + k]; }
  const float inv = 1.0f / (float)(2048LL << log2S);
  const float m = s * inv;
  float var = fmaf(-m, m, s2 * inv);   // biased variance
  var = fmaxf(var, 0.f);
  const float r = 1.0f / sqrtf(var + 1e-5f);
  const float av = g[c] * r;
  a[c] = av;
  bb[c] = fmaf(-m, av, be[c]);
}

// ---------------- BN affine + tanh, in place, 8 bf16 per thread -------------
__global__ __launch_bounds__(256) void bnact_kernel(u16* __restrict__ y,
                                                    const float* __restrict__ a,
                                                    const float* __restrict__ bb,
                                                    int C, int log2S) {
  const size_t i = (size_t)blockIdx.x * 256 + threadIdx.x;  // vec-8 index
  uint4 raw = reinterpret_cast<uint4*>(y)[i];
  const int c = (int)(((i * 8) >> log2S)) & (C - 1);
  const float aa = a[c], b2 = bb[c];
  u32 wq[4] = {raw.x, raw.y, raw.z, raw.w};
  #pragma unroll
  for (int q = 0; q < 4; ++q) {
    const float lo = tanhf(fmaf(bf2f((u16)(wq[q] & 0xffffu)), aa, b2));
    const float hi = tanhf(fmaf(bf2f((u16)(wq[q] >> 16)), aa, b2));
    wq[q] = (u32)f2bf(lo) | ((u32)f2bf(hi) << 16);
  }
  raw.x = wq[0]; raw.y = wq[1]; raw.z = wq[2]; raw.w = wq[3];
  reinterpret_cast<uint4*>(y)[i] = raw;
}

// ---------------- generic ConvT k=4 s=2 p=1, bf16 in/out, fp32 math ---------
// out[b,o,oy,ox] = sum_c sum_taps in[b,c,iy,ix] * w[c, o_gbase+o, ky,kx]
// oy = 2*iy + ky - 1 (pad 1), handled branch-free via zero-padded LDS tile.
template <int CIN, int COUT_W, int SIN, int BT, int OT, int PS>
__global__ __launch_bounds__(256) void convt_kernel(const u16* __restrict__ in,
                                                    const float* __restrict__ w,
                                                    const float* __restrict__ bias,
                                                    u16* __restrict__ outp,
                                                    int o_gbase, int c_store) {
  constexpr int SOUT = 2 * SIN;
  constexpr int RPT = SOUT / PS;       // output rows per thread (even)
  constexpr int HR = RPT / 2;          // sy rows per thread
  constexpr int NR = HR + 2;           // padded input rows needed
  constexpr int BC = 16;               // input-channel chunk
  constexpr int SP = SIN + 2;          // padded spatial
  constexpr int RW = (SP + 3) & ~3;    // padded row width (float4 aligned)
  constexpr int CSTR = SP * RW;
  constexpr int BSTR = BC * CSTR + 4;
  constexpr int ISIZE = BT * BSTR;
  constexpr int WR = 20;               // 16 taps padded to 20
  static_assert(BT * OT * PS == 256, "block shape");
  static_assert((RPT & 1) == 0, "RPT even");
  static_assert((SIN & 3) == 0, "SIN mult of 4");
  __shared__ float Is[ISIZE];
  __shared__ float Ws[BC * OT * WR];
  const int t = threadIdx.x;
  const int o_l = t % OT;
  const int b_l = (t / OT) % BT;
  const int ph = t / (OT * BT);
  const int b0 = blockIdx.y * BT;
  const int o0 = blockIdx.x * OT;

  float acc[RPT][SOUT];
  #pragma unroll
  for (int i = 0; i < RPT; ++i)
    #pragma unroll
    for (int j = 0; j < SOUT; ++j) acc[i][j] = 0.f;

  // zero padded tile once (borders stay zero; interior rewritten per chunk)
  for (int i = t; i < ISIZE; i += 256) Is[i] = 0.f;

  for (int c0 = 0; c0 < CIN; c0 += BC) {
    __syncthreads();  // previous chunk's reads done / zeros visible
    // stage weights [BC][OT][16]
    for (int i = t; i < BC * OT * 16; i += 256) {
      const int c = i / (OT * 16);
      const int rem = i % (OT * 16);
      const int o = rem / 16;
      const int tap = rem % 16;
      Ws[c * (OT * WR) + o * WR + tap] =
          w[(((size_t)(c0 + c)) * COUT_W + (o_gbase + o0 + o)) * 16 + tap];
    }
    // fill interior (bf16 -> fp32), 4 elems per thread-iter
    constexpr int FILLE = BT * BC * SIN * SIN;
    for (int i = t * 4; i < FILLE; i += 1024) {
      const int bb_ = i / (BC * SIN * SIN);
      const int rem = i % (BC * SIN * SIN);
      const int c = rem / (SIN * SIN);
      const int p = rem % (SIN * SIN);
      const int iy = p / SIN;
      const int ix = p % SIN;
      const ushort4 r4 = *reinterpret_cast<const ushort4*>(
          in + (((size_t)(b0 + bb_)) * CIN + (c0 + c)) * (SIN * SIN) + p);
      float* dst = &Is[bb_ * BSTR + c * CSTR + (iy + 1) * RW + (ix + 1)];
      dst[0] = bf2f(r4.x); dst[1] = bf2f(r4.y); dst[2] = bf2f(r4.z); dst[3] = bf2f(r4.w);
    }
    __syncthreads();

    const int row0 = ph * HR;
    const int ibase = b_l * BSTR + row0 * RW;
    const int wbase = o_l * WR;
    for (int c = 0; c < BC; ++c) {
      float wv[16];
      #pragma unroll
      for (int q = 0; q < 4; ++q) {
        const float4 tw = *reinterpret_cast<const float4*>(&Ws[c * (OT * WR) + wbase + q * 4]);
        wv[q * 4 + 0] = tw.x; wv[q * 4 + 1] = tw.y; wv[q * 4 + 2] = tw.z; wv[q * 4 + 3] = tw.w;
      }
      float iv[NR][RW];
      #pragma unroll
      for (int r = 0; r < NR; ++r)
        #pragma unroll
        for (int q = 0; q < RW / 4; ++q) {
          const float4 ti = *reinterpret_cast<const float4*>(&Is[ibase + c * CSTR + r * RW + q * 4]);
          iv[r][q * 4 + 0] = ti.x; iv[r][q * 4 + 1] = ti.y;
          iv[r][q * 4 + 2] = ti.z; iv[r][q * 4 + 3] = ti.w;
        }
      #pragma unroll
      for (int dy = 0; dy < RPT; ++dy) {
        const int par = dy & 1;      // oy parity (ph*RPT is even)
        const int syl = dy >> 1;
        #pragma unroll
        for (int ox = 0; ox < SOUT; ++ox) {
          const int pxp = ox & 1;
          const int sx = ox >> 1;
          float aa = acc[dy][ox];
          #pragma unroll
          for (int jy = 0; jy < 2; ++jy) {
            const int r = par ? (syl + 2 - jy) : (syl + 1 - jy);
            const int ky = par ? (2 * jy) : (2 * jy + 1);
            #pragma unroll
            for (int jx = 0; jx < 2; ++jx) {
              const int xc = pxp ? (sx + 2 - jx) : (sx + 1 - jx);
              const int kx = pxp ? (2 * jx) : (2 * jx + 1);
              aa = fmaf(iv[r][xc], wv[ky * 4 + kx], aa);
            }
          }
          acc[dy][ox] = aa;
        }
      }
    }
  }
  const float bo = bias[o_gbase + o0 + o_l];
  const size_t obase = (((size_t)(b0 + b_l)) * c_store + (o0 + o_l)) * (size_t)(SOUT * SOUT);
  #pragma unroll
  for (int dy = 0; dy < RPT; ++dy) {
    const int oy = ph * RPT + dy;
    #pragma unroll
    for (int xb = 0; xb < SOUT; xb += 8) {
      union { u16 s[8]; uint4 v; } pk;
      #pragma unroll
      for (int j = 0; j < 8; ++j) pk.s[j] = f2bf(acc[dy][xb + j] + bo);
      *reinterpret_cast<uint4*>(&outp[obase + (size_t)oy * SOUT + xb]) = pk.v;
    }
  }
}

// ---------------- conv4 partial: 32-ch slice of h3 -> accumulate d_out ------
__global__ __launch_bounds__(256) void conv4_kernel(const u16* __restrict__ h3c,
                                                    const float* __restrict__ w4,
                                                    const float* __restrict__ b4,
                                                    float* __restrict__ outp,
                                                    int cbase, int last) {
  const int b = blockIdx.x;
  const int t = threadIdx.x;
  __shared__ float wsh[32 * 16];
  __shared__ float is[32 * 256];   // 32 channels x 16x16, fp32
  for (int i = t; i < 512; i += 256) wsh[i] = w4[cbase * 16 + i];
  for (int i = t * 8; i < 32 * 256; i += 2048) {
    const uint4 raw = *reinterpret_cast<const uint4*>(
        h3c + ((size_t)b * 32 + (i >> 8)) * 256 + (i & 255));
    const u32 wq[4] = {raw.x, raw.y, raw.z, raw.w};
    float* dst = &is[i];
    #pragma unroll
    for (int q = 0; q < 4; ++q) {
      dst[q * 2 + 0] = bf2f((u16)(wq[q] & 0xffffu));
      dst[q * 2 + 1] = bf2f((u16)(wq[q] >> 16));
    }
  }
  __syncthreads();
  float acc[4] = {0.f, 0.f, 0.f, 0.f};
  const int ox = t & 31;
  const int oy0 = t >> 5;
  for (int c = 0; c < 32; ++c) {
    #pragma unroll
    for (int k = 0; k < 4; ++k) {
      const int oy = oy0 + 8 * k;
      #pragma unroll
      for (int jy = 0; jy < 2; ++jy) {
        const int ky = 2 * jy + 1 - (oy & 1);
        const int iyn = oy + 1 - ky;
        if ((unsigned)iyn < 32u) {
          const int iy = iyn >> 1;
          #pragma unroll
          for (int jx = 0; jx < 2; ++jx) {
            const int kx = 2 * jx + 1 - (ox & 1);
            const int ixn = ox + 1 - kx;
            if ((unsigned)ixn < 32u) {
              const int ix = ixn >> 1;
              acc[k] = fmaf(is[c * 256 + iy * 16 + ix], wsh[c * 16 + ky * 4 + kx], acc[k]);
            }
          }
        }
      }
    }
  }
  #pragma unroll
  for (int k = 0; k < 4; ++k) {
    const int oy = oy0 + 8 * k;
    const size_t ob = (size_t)b * 1024 + oy * 32 + ox;
    const float base = (cbase == 0) ? b4[0] : outp[ob];
    const float v = base + acc[k];
    outp[ob] = last ? (1.0f / (1.0f + expf(-v))) : v;
  }
}

// ----------------------------------------------------------------------------
extern "C" void kernel_launch(void* const* d_in, const int* in_sizes, int n_in,
                              void* d_out, int out_size, void* d_ws, size_t ws_size,
                              hipStream_t stream) {
  (void)in_sizes; (void)n_in; (void)out_size; (void)ws_size;
  const float* x   = (const float*)d_in[0];
  const float* w1  = (const float*)d_in[1];
  const float* b1  = (const float*)d_in[2];
  const float* g1  = (const float*)d_in[3];
  const float* be1 = (const float*)d_in[4];
  const float* w2  = (const float*)d_in[5];
  const float* b2  = (const float*)d_in[6];
  const float* g2  = (const float*)d_in[7];
  const float* be2 = (const float*)d_in[8];
  const float* w3  = (const float*)d_in[9];
  const float* b3  = (const float*)d_in[10];
  const float* g3  = (const float*)d_in[11];
  const float* be3 = (const float*)d_in[12];
  const float* w4  = (const float*)d_in[13];
  const float* b4  = (const float*)d_in[14];

  char* ws = (char*)d_ws;
  u16*   y2   = (u16*)(ws + 0);            // 64MB
  u16*   y1   = (u16*)(ws + 67108864);     // 32MB
  u16*   y3c  = (u16*)(ws + 100663296);    // 32MB
  float* vals = (float*)(ws + 134217728);
  int*   idxs = (int*)(ws + 134627328);
  float* sp   = (float*)(ws + 135036928);
  float* sqp  = (float*)(ws + 135053312);
  float* ac   = (float*)(ws + 135069696);
  float* bc   = (float*)(ws + 135071744);
  float* outp = (float*)d_out;

  // truncation vector (sparse form)
  topk_kernel<<<2048, 256, 0, stream>>>(x, vals, idxs);

  // layer 1: sparse conv1 -> y1 [2048,512,4,4] bf16; BN1; tanh in place
  conv1_kernel<<<dim3(8, 2048), 256, 0, stream>>>(vals, idxs, w1, b1, y1);
  bnstats_part_kernel<<<dim3(512, 8), 256, 0, stream>>>(y1, sp, sqp, 512, 4);
  bnfinalize_kernel<<<2, 256, 0, stream>>>(sp, sqp, g1, be1, ac, bc, 512, 4);
  bnact_kernel<<<8192, 256, 0, stream>>>(y1, ac, bc, 512, 4);

  // layer 2: convT 512->256, 4x4 -> 8x8 -> y2 bf16; BN2; tanh
  convt_kernel<512, 256, 4, 8, 16, 2><<<dim3(16, 256), 256, 0, stream>>>(
      y1, w2, b2, y2, 0, 256);
  bnstats_part_kernel<<<dim3(256, 8), 256, 0, stream>>>(y2, sp, sqp, 256, 6);
  bnfinalize_kernel<<<1, 256, 0, stream>>>(sp, sqp, g2, be2, ac, bc, 256, 6);
  bnact_kernel<<<16384, 256, 0, stream>>>(y2, ac, bc, 256, 6);

  // layer 3+4: conv3 in 4 chunks of 32 output channels; conv4 accumulates
  for (int ch = 0; ch < 4; ++ch) {
    const int cbase = ch * 32;
    convt_kernel<256, 128, 8, 4, 8, 8><<<dim3(4, 512), 256, 0, stream>>>(
        y2, w3, b3, y3c, cbase, 32);
    bnstats_part_kernel<<<dim3(32, 8), 256, 0, stream>>>(y3c, sp, sqp, 32, 8);
    bnfinalize_kernel<<<1, 256, 0, stream>>>(sp, sqp, g3 + cbase, be3 + cbase, ac, bc, 32, 8);
    bnact_kernel<<<8192, 256, 0, stream>>>(y3c, ac, bc, 32, 8);
    conv4_kernel<<<2048, 256, 0, stream>>>(y3c, w4, b4, outp, cbase, ch == 3);
  }
}

// Round 3
// 1575.851 us; speedup vs baseline: 2.5167x; 2.5167x over previous
//
#include <hip/hip_runtime.h>
#include <cstdint>
#include <cstddef>

// ----------------------------------------------------------------------------
// R3: MFMA bf16 convT pipeline, channels-last activations, fp32 BN math.
// Workspace (bytes), all aliases sequenced by stream order; max end 135,036,928
// (<= R2-proven 135,073,792):
//   y2   @ 0           64MB  [2048][64][256] bf16
//   y1   @ 67108864    32MB  [2048][16][512] bf16   (dead after conv2)
//   w3t  @ 67108864    1MB   [128][16][256]  bf16   (written after conv2)
//   y3c  @ 100663296   32MB  [2048][256][32] bf16   (written at conv3)
//   w1t  @ 100663296   16MB  [1000][16][512] bf16   (dead after conv1)
//   w2t  @ 117047296   4MB   [256][16][512]  bf16   (dead after conv2)
//   vals @ 134217728, idxs @ 134627328               (dead after conv1)
//   sp   @ 134217728, sqp @ 134479872, ac @ 134742016, bc @ 134744064
// ----------------------------------------------------------------------------

typedef unsigned short u16;
typedef unsigned int u32;
typedef __attribute__((ext_vector_type(8))) short s16x8;   // 8 bf16 (4 VGPR)
typedef __attribute__((ext_vector_type(4))) float f32x4;

static __device__ __forceinline__ float bf2f(u16 u) {
  union { u32 i; float f; } v; v.i = ((u32)u) << 16; return v.f;
}
static __device__ __forceinline__ u16 f2bf(float f) {  // RNE
  union { float f; u32 i; } v; v.f = f;
  const u32 r = v.i + 0x7fffu + ((v.i >> 16) & 1u);
  return (u16)(r >> 16);
}

// ---------------- top-k(50) + log/clamp/shift (unchanged, proven) -----------
__global__ __launch_bounds__(256) void topk_kernel(const float* __restrict__ x,
                                                   float* __restrict__ vals,
                                                   int* __restrict__ idxs) {
  const int b = blockIdx.x;
  const int t = threadIdx.x;
  __shared__ float sv[1024];
  __shared__ float redv[4];
  __shared__ int redi[4];
  __shared__ float tv[50];
  __shared__ int ti[50];
  __shared__ float sshift;
  for (int i = t; i < 1000; i += 256) sv[i] = x[(size_t)b * 1000 + i];
  for (int i = 1000 + t; i < 1024; i += 256) sv[i] = -INFINITY;
  __syncthreads();
  for (int k = 0; k < 50; ++k) {
    float bv = -INFINITY;
    int bi = 0x7fffffff;
    #pragma unroll
    for (int s = 0; s < 4; ++s) {
      const int i = t + s * 256;
      const float v = sv[i];
      if (v > bv) { bv = v; bi = i; }
    }
    for (int off = 32; off > 0; off >>= 1) {
      const float ov = __shfl_down(bv, off);
      const int oi = __shfl_down(bi, off);
      if (ov > bv || (ov == bv && oi < bi)) { bv = ov; bi = oi; }
    }
    if ((t & 63) == 0) { redv[t >> 6] = bv; redi[t >> 6] = bi; }
    __syncthreads();
    if (t == 0) {
      for (int w = 1; w < 4; ++w)
        if (redv[w] > bv || (redv[w] == bv && redi[w] < bi)) { bv = redv[w]; bi = redi[w]; }
      tv[k] = bv;
      ti[k] = bi;
      sv[bi] = -INFINITY;
    }
    __syncthreads();
  }
  if (t < 50) tv[t] = fmaxf(logf(tv[t]), -1000.0f) + 50.0f;
  __syncthreads();
  if (t == 0) {
    float mn = tv[0];
    for (int k = 1; k < 50; ++k) mn = fminf(mn, tv[k]);
    sshift = fmaxf(-mn, 0.0f);
  }
  __syncthreads();
  if (t < 50) {
    vals[b * 50 + t] = tv[t] + sshift;
    idxs[b * 50 + t] = ti[t];
  }
}

// ---------------- w1 transpose: [1000][512][16] f32 -> [1000][16][512] bf16 -
__global__ __launch_bounds__(256) void w1t_kernel(const float* __restrict__ w1,
                                                  u16* __restrict__ w1t) {
  const int cin = blockIdx.x;
  const int t = threadIdx.x;
  __shared__ float is[512 * 17];
  const float* src = w1 + (size_t)cin * 8192;
  #pragma unroll
  for (int r = 0; r < 8; ++r) {
    const int f = r * 1024 + t * 4;
    const float4 v = *reinterpret_cast<const float4*>(src + f);
    const int co = f >> 4, s = f & 15;   // s..s+3, same co
    is[co * 17 + s + 0] = v.x;
    is[co * 17 + s + 1] = v.y;
    is[co * 17 + s + 2] = v.z;
    is[co * 17 + s + 3] = v.w;
  }
  __syncthreads();
  u16* dst = w1t + (size_t)cin * 8192;
  #pragma unroll
  for (int p = 0; p < 4; ++p) {
    const int i8 = (p * 256 + t) * 8;    // flat = s*512 + co
    const int s = i8 >> 9, co = i8 & 511;
    union { u16 h[8]; s16x8 v; } pk;
    #pragma unroll
    for (int q = 0; q < 8; ++q) pk.h[q] = f2bf(is[(co + q) * 17 + s]);
    *reinterpret_cast<s16x8*>(dst + i8) = pk.v;
  }
}

// ---------------- w2/w3 transpose: [CIN][COUT][16] f32 -> [COUT][16][CIN] bf16
template <int CIN, int COUT>
__global__ __launch_bounds__(256) void wt_kernel(const float* __restrict__ w,
                                                 u16* __restrict__ wt) {
  const int o = blockIdx.x;
  const int t = threadIdx.x;
  __shared__ __align__(16) u16 tile[16 * CIN];
  for (int c = t; c < CIN; c += 256) {
    const float* src = w + ((size_t)c * COUT + o) * 16;
    #pragma unroll
    for (int q4 = 0; q4 < 4; ++q4) {
      const float4 v = *reinterpret_cast<const float4*>(src + q4 * 4);
      tile[(q4 * 4 + 0) * CIN + c] = f2bf(v.x);
      tile[(q4 * 4 + 1) * CIN + c] = f2bf(v.y);
      tile[(q4 * 4 + 2) * CIN + c] = f2bf(v.z);
      tile[(q4 * 4 + 3) * CIN + c] = f2bf(v.w);
    }
  }
  __syncthreads();
  u16* dst = wt + (size_t)o * 16 * CIN;
  for (int i8 = t * 8; i8 < 16 * CIN; i8 += 2048)
    *reinterpret_cast<s16x8*>(dst + i8) = *reinterpret_cast<const s16x8*>(tile + i8);
}

// ---------------- conv1: sparse gather, channels-last y1 [2048][16][512] ----
__global__ __launch_bounds__(256) void conv1_kernel(const float* __restrict__ vals,
                                                    const int* __restrict__ idxs,
                                                    const u16* __restrict__ w1t,
                                                    const float* __restrict__ b1,
                                                    u16* __restrict__ y1) {
  const int b = blockIdx.x;
  const int t = threadIdx.x;
  __shared__ float sval[50];
  __shared__ int sidx[50];
  if (t < 50) { sval[t] = vals[b * 50 + t]; sidx[t] = idxs[b * 50 + t]; }
  __syncthreads();
  const int co = (t & 63) * 8;
  const int s0 = t >> 6;
  float b8[8];
  #pragma unroll
  for (int q = 0; q < 8; ++q) b8[q] = b1[co + q];
  #pragma unroll
  for (int sp = 0; sp < 4; ++sp) {
    const int s = sp * 4 + s0;
    float acc[8] = {0.f, 0.f, 0.f, 0.f, 0.f, 0.f, 0.f, 0.f};
    for (int j = 0; j < 50; ++j) {
      const float v = sval[j];
      union { s16x8 v8; u16 h[8]; } w;
      w.v8 = *reinterpret_cast<const s16x8*>(w1t + (size_t)sidx[j] * 8192 + s * 512 + co);
      #pragma unroll
      for (int q = 0; q < 8; ++q) acc[q] = fmaf(v, bf2f(w.h[q]), acc[q]);
    }
    union { u16 h[8]; s16x8 v8; } o;
    #pragma unroll
    for (int q = 0; q < 8; ++q) o.h[q] = f2bf(acc[q] + b8[q]);
    *reinterpret_cast<s16x8*>(y1 + (size_t)b * 8192 + s * 512 + co) = o.v8;
  }
}

// ---------------- BN stats, channels-last [ROWS][C] (128 splits) ------------
__global__ __launch_bounds__(256) void bnstats_kernel(const u16* __restrict__ y,
                                                      float* __restrict__ sp,
                                                      float* __restrict__ sqp,
                                                      int C, int CB, int ROWS) {
  const int PB = CB >> 1;          // channel pairs per block
  const int PR = 256 / PB;         // row groups
  const int t = threadIdx.x;
  const int cp = t & (PB - 1);
  const int rl = t / PB;
  const int cbase = blockIdx.x * CB;
  const int split = blockIdx.y;
  const int RPB = ROWS >> 7;
  const u16* base = y + (size_t)split * RPB * C + cbase + 2 * cp;
  float s0 = 0.f, s1 = 0.f, q0 = 0.f, q1 = 0.f;
  for (int r = rl; r < RPB; r += PR) {
    const u32 raw = *reinterpret_cast<const u32*>(base + (size_t)r * C);
    const float a = bf2f((u16)(raw & 0xffffu));
    const float b = bf2f((u16)(raw >> 16));
    s0 += a; s1 += b;
    q0 = fmaf(a, a, q0); q1 = fmaf(b, b, q1);
  }
  __shared__ float4 arr[256];
  arr[t] = make_float4(s0, s1, q0, q1);
  __syncthreads();
  if (t < PB) {
    float4 acc = arr[t];
    for (int g = 1; g < PR; ++g) {
      const float4 v = arr[g * PB + t];
      acc.x += v.x; acc.y += v.y; acc.z += v.z; acc.w += v.w;
    }
    const int c = cbase + 2 * t;
    sp[split * C + c] = acc.x;
    sp[split * C + c + 1] = acc.y;
    sqp[split * C + c] = acc.z;
    sqp[split * C + c + 1] = acc.w;
  }
}

__global__ __launch_bounds__(256) void bnfin_kernel(const float* __restrict__ sp,
                                                    const float* __restrict__ sqp,
                                                    const float* __restrict__ g,
                                                    const float* __restrict__ be,
                                                    float* __restrict__ a,
                                                    float* __restrict__ bb,
                                                    int C, float inv) {
  const int c = blockIdx.x * 256 + threadIdx.x;
  if (c >= C) return;
  float s = 0.f, s2 = 0.f;
  for (int k = 0; k < 128; ++k) { s += sp[k * C + c]; s2 += sqp[k * C + c]; }
  const float m = s * inv;
  float var = fmaf(-m, m, s2 * inv);
  var = fmaxf(var, 0.f);
  const float r = 1.0f / sqrtf(var + 1e-5f);
  const float av = g[c] * r;
  a[c] = av;
  bb[c] = fmaf(-m, av, be[c]);
}

// ---------------- BN affine + tanh in place, channels-last ------------------
__global__ __launch_bounds__(256) void bnact_kernel(u16* __restrict__ y,
                                                    const float* __restrict__ a,
                                                    const float* __restrict__ bb,
                                                    int Cm1) {
  const size_t i = ((size_t)blockIdx.x * 256 + threadIdx.x) * 8;
  const int c = (int)i & Cm1;
  uint4 raw = *reinterpret_cast<uint4*>(y + i);
  float av[8], bv[8];
  *reinterpret_cast<float4*>(av) = *reinterpret_cast<const float4*>(a + c);
  *reinterpret_cast<float4*>(av + 4) = *reinterpret_cast<const float4*>(a + c + 4);
  *reinterpret_cast<float4*>(bv) = *reinterpret_cast<const float4*>(bb + c);
  *reinterpret_cast<float4*>(bv + 4) = *reinterpret_cast<const float4*>(bb + c + 4);
  u32 w[4] = {raw.x, raw.y, raw.z, raw.w};
  #pragma unroll
  for (int q = 0; q < 4; ++q) {
    const float lo = tanhf(fmaf(bf2f((u16)(w[q] & 0xffffu)), av[2 * q], bv[2 * q]));
    const float hi = tanhf(fmaf(bf2f((u16)(w[q] >> 16)), av[2 * q + 1], bv[2 * q + 1]));
    w[q] = (u32)f2bf(lo) | ((u32)f2bf(hi) << 16);
  }
  raw.x = w[0]; raw.y = w[1]; raw.z = w[2]; raw.w = w[3];
  *reinterpret_cast<uint4*>(y + i) = raw;
}

// ---------------- MFMA convT k=4 s=2 p=1 ------------------------------------
// in: [B][SIN*SIN][CIN] bf16 channels-last. wt: [COUT_W][16][CIN] bf16.
// out: [B][4*SIN*SIN][COUT_STORE] bf16, out channel slice [o_gbase, +NB*gridx).
// Per parity (py,px): out(2sy+py,2sx+px) = sum_j in(sy+DY[py][j], sx+DX..) * w[ky,kx]
__global__ void dummy_never(){}

template <int SIN, int CIN, int WM, int WN, int MBATCH, int COUT_STORE>
__global__ __launch_bounds__(256) void convt_mfma(const u16* __restrict__ in,
                                                  const u16* __restrict__ wt,
                                                  const float* __restrict__ bias,
                                                  u16* __restrict__ outp,
                                                  int o_gbase) {
  constexpr int SS = SIN * SIN;
  constexpr int MB = MBATCH * SS;          // input rows per block
  constexpr int MFR = MB / (16 * WM);      // m-frags per wave
  constexpr int NB = WN * 16;              // out channels per block
  constexpr int LOGS = (SIN == 4) ? 2 : 3;
  constexpr int KYT[2][2] = {{1, 3}, {2, 0}};
  constexpr int DYT[2][2] = {{0, -1}, {0, 1}};
  static_assert(MB % 32 == 0, "staging");
  __shared__ __align__(16) u16 As[(MB + 1) * 64];   // swizzled [MB+1][64]

  const int t = threadIdx.x;
  const int lane = t & 63;
  const int wave = t >> 6;
  const int wn = wave % WN;
  const int wm = wave / WN;
  const int l15 = lane & 15;
  const int kl = lane >> 4;
  const int bx = blockIdx.x;
  const int R0 = blockIdx.y * MB;

  // row-base addresses for the 9 shifts x MFR frags (swizzle pre-folded)
  int rb[9][MFR];
  #pragma unroll
  for (int m = 0; m < MFR; ++m) {
    const int r = wm * (MB / WM) + m * 16 + l15;
    const int bl = r >> (2 * LOGS);
    const int rr = r & (SS - 1);
    const int sy = rr >> LOGS, sx = rr & (SIN - 1);
    #pragma unroll
    for (int dyi = 0; dyi < 3; ++dyi)
      #pragma unroll
      for (int dxi = 0; dxi < 3; ++dxi) {
        const int ny = sy + dyi - 1, nx = sx + dxi - 1;
        const bool ok = (ny >= 0 && ny < SIN && nx >= 0 && nx < SIN);
        const int rp = ok ? ((bl << (2 * LOGS)) + (ny << LOGS) + nx) : MB;
        rb[dyi * 3 + dxi][m] = (rp << 7) | ((rp & 7) << 4);
      }
  }
  if (t < 8) { s16x8 z = {}; *reinterpret_cast<s16x8*>(As + MB * 64 + t * 8) = z; }

  f32x4 acc[2][2][MFR];
  #pragma unroll
  for (int py = 0; py < 2; ++py)
    #pragma unroll
    for (int px = 0; px < 2; ++px)
      #pragma unroll
      for (int m = 0; m < MFR; ++m) acc[py][px][m] = (f32x4){0.f, 0.f, 0.f, 0.f};

  const int ocol = o_gbase + bx * NB + wn * 16 + l15;   // absolute out channel
  const size_t wbase = (size_t)ocol * 16 * CIN + kl * 8;
  const int kl16 = kl * 16;

  for (int c0 = 0; c0 < CIN; c0 += 64) {
    __syncthreads();
    #pragma unroll
    for (int pass = 0; pass < MB / 32; ++pass) {
      const int row = pass * 32 + (t >> 3);
      const int co8 = (t & 7) * 8;
      const s16x8 v = *reinterpret_cast<const s16x8*>(
          in + (size_t)(R0 + row) * CIN + c0 + co8);
      const int db = row * 128 + ((co8 * 2) ^ ((row & 7) << 4));
      *reinterpret_cast<s16x8*>((char*)As + db) = v;
    }
    __syncthreads();
    #pragma unroll
    for (int kh = 0; kh < 2; ++kh) {
      const int koff = kh * 64 + kl16;
      const size_t kw = wbase + c0 + kh * 32;
      s16x8 bf[2][2][2][2];
      #pragma unroll
      for (int py = 0; py < 2; ++py)
        #pragma unroll
        for (int px = 0; px < 2; ++px)
          #pragma unroll
          for (int jy = 0; jy < 2; ++jy)
            #pragma unroll
            for (int jx = 0; jx < 2; ++jx) {
              const int tap = KYT[py][jy] * 4 + KYT[px][jx];
              bf[py][px][jy][jx] =
                  *reinterpret_cast<const s16x8*>(wt + kw + (size_t)tap * CIN);
            }
      #pragma unroll
      for (int m = 0; m < MFR; ++m) {
        s16x8 af[9];
        #pragma unroll
        for (int s9 = 0; s9 < 9; ++s9)
          af[s9] = *reinterpret_cast<const s16x8*>((char*)As + (rb[s9][m] ^ koff));
        #pragma unroll
        for (int py = 0; py < 2; ++py)
          #pragma unroll
          for (int px = 0; px < 2; ++px)
            #pragma unroll
            for (int jy = 0; jy < 2; ++jy)
              #pragma unroll
              for (int jx = 0; jx < 2; ++jx) {
                const int s9 = (DYT[py][jy] + 1) * 3 + (DYT[px][jx] + 1);
                acc[py][px][m] = __builtin_amdgcn_mfma_f32_16x16x32_bf16(
                    af[s9], bf[py][px][jy][jx], acc[py][px][m], 0, 0, 0);
              }
      }
    }
  }

  const int cstore = bx * NB + wn * 16 + l15;
  const float bo = bias[ocol];
  const int B0 = blockIdx.y * MBATCH;
  #pragma unroll
  for (int m = 0; m < MFR; ++m)
    #pragma unroll
    for (int i = 0; i < 4; ++i) {
      const int r = wm * (MB / WM) + m * 16 + kl * 4 + i;
      const int bl = r >> (2 * LOGS);
      const int rr = r & (SS - 1);
      const int sy = rr >> LOGS, sx = rr & (SIN - 1);
      const size_t ob = (size_t)(B0 + bl) * 4 * SS;
      #pragma unroll
      for (int py = 0; py < 2; ++py)
        #pragma unroll
        for (int px = 0; px < 2; ++px) {
          const int od = (2 * sy + py) * (2 * SIN) + 2 * sx + px;
          outp[(ob + od) * COUT_STORE + cstore] = f2bf(acc[py][px][m][i] + bo);
        }
    }
}

// ---------------- conv4: 32-ch slice of channels-last h3 -> accumulate out --
__global__ __launch_bounds__(256) void conv4_kernel(const u16* __restrict__ h3c,
                                                    const float* __restrict__ w4,
                                                    const float* __restrict__ b4,
                                                    float* __restrict__ outp,
                                                    int cbase, int last) {
  const int b = blockIdx.x;
  const int t = threadIdx.x;
  __shared__ float wsh[32 * 16];
  __shared__ float is[32 * 257];
  for (int i = t; i < 512; i += 256) wsh[i] = w4[cbase * 16 + i];
  #pragma unroll
  for (int p = 0; p < 4; ++p) {
    const int idx8 = p * 256 + t;
    const int s = idx8 >> 2;
    const int c0 = (idx8 & 3) * 8;
    union { s16x8 v8; u16 h[8]; } r;
    r.v8 = *reinterpret_cast<const s16x8*>(h3c + ((size_t)b * 256 + s) * 32 + c0);
    #pragma unroll
    for (int q = 0; q < 8; ++q) is[(c0 + q) * 257 + s] = bf2f(r.h[q]);
  }
  __syncthreads();
  float acc[4] = {0.f, 0.f, 0.f, 0.f};
  const int ox = t & 31;
  const int oy0 = t >> 5;
  for (int c = 0; c < 32; ++c) {
    #pragma unroll
    for (int k = 0; k < 4; ++k) {
      const int oy = oy0 + 8 * k;
      #pragma unroll
      for (int jy = 0; jy < 2; ++jy) {
        const int ky = 2 * jy + 1 - (oy & 1);
        const int iyn = oy + 1 - ky;
        if ((unsigned)iyn < 32u) {
          const int iy = iyn >> 1;
          #pragma unroll
          for (int jx = 0; jx < 2; ++jx) {
            const int kx = 2 * jx + 1 - (ox & 1);
            const int ixn = ox + 1 - kx;
            if ((unsigned)ixn < 32u) {
              const int ix = ixn >> 1;
              acc[k] = fmaf(is[c * 257 + iy * 16 + ix], wsh[c * 16 + ky * 4 + kx], acc[k]);
            }
          }
        }
      }
    }
  }
  #pragma unroll
  for (int k = 0; k < 4; ++k) {
    const int oy = oy0 + 8 * k;
    const size_t ob = (size_t)b * 1024 + oy * 32 + ox;
    const float base = (cbase == 0) ? b4[0] : outp[ob];
    const float v = base + acc[k];
    outp[ob] = last ? (1.0f / (1.0f + expf(-v))) : v;
  }
}

// ----------------------------------------------------------------------------
extern "C" void kernel_launch(void* const* d_in, const int* in_sizes, int n_in,
                              void* d_out, int out_size, void* d_ws, size_t ws_size,
                              hipStream_t stream) {
  (void)in_sizes; (void)n_in; (void)out_size; (void)ws_size;
  const float* x   = (const float*)d_in[0];
  const float* w1  = (const float*)d_in[1];
  const float* b1  = (const float*)d_in[2];
  const float* g1  = (const float*)d_in[3];
  const float* be1 = (const float*)d_in[4];
  const float* w2  = (const float*)d_in[5];
  const float* b2  = (const float*)d_in[6];
  const float* g2  = (const float*)d_in[7];
  const float* be2 = (const float*)d_in[8];
  const float* w3  = (const float*)d_in[9];
  const float* b3  = (const float*)d_in[10];
  const float* g3  = (const float*)d_in[11];
  const float* be3 = (const float*)d_in[12];
  const float* w4  = (const float*)d_in[13];
  const float* b4  = (const float*)d_in[14];

  char* ws = (char*)d_ws;
  u16*   y2   = (u16*)(ws + 0);
  u16*   y1   = (u16*)(ws + 67108864);
  u16*   w3t  = (u16*)(ws + 67108864);    // after conv2 (aliases y1)
  u16*   y3c  = (u16*)(ws + 100663296);
  u16*   w1t  = (u16*)(ws + 100663296);   // dead after conv1 (aliases y3c)
  u16*   w2t  = (u16*)(ws + 117047296);   // dead after conv2 (aliases y3c)
  float* vals = (float*)(ws + 134217728);
  int*   idxs = (int*)(ws + 134627328);
  float* sp   = (float*)(ws + 134217728); // after conv1 (aliases vals)
  float* sqp  = (float*)(ws + 134479872);
  float* ac   = (float*)(ws + 134742016);
  float* bc   = (float*)(ws + 134744064);
  float* outp = (float*)d_out;

  // precomputes + truncation vector
  w1t_kernel<<<1000, 256, 0, stream>>>(w1, w1t);
  wt_kernel<512, 256><<<256, 256, 0, stream>>>(w2, w2t);
  topk_kernel<<<2048, 256, 0, stream>>>(x, vals, idxs);

  // layer 1
  conv1_kernel<<<2048, 256, 0, stream>>>(vals, idxs, w1t, b1, y1);
  bnstats_kernel<<<dim3(4, 128), 256, 0, stream>>>(y1, sp, sqp, 512, 128, 32768);
  bnfin_kernel<<<2, 256, 0, stream>>>(sp, sqp, g1, be1, ac, bc, 512, 1.0f / 32768.0f);
  bnact_kernel<<<8192, 256, 0, stream>>>(y1, ac, bc, 511);

  // layer 2: MFMA convT 512->256, 4x4 -> 8x8
  convt_mfma<4, 512, 1, 4, 4, 256><<<dim3(4, 512), 256, 0, stream>>>(y1, w2t, b2, y2, 0);
  wt_kernel<256, 128><<<128, 256, 0, stream>>>(w3, w3t);
  bnstats_kernel<<<dim3(2, 128), 256, 0, stream>>>(y2, sp, sqp, 256, 128, 131072);
  bnfin_kernel<<<1, 256, 0, stream>>>(sp, sqp, g2, be2, ac, bc, 256, 1.0f / 131072.0f);
  bnact_kernel<<<16384, 256, 0, stream>>>(y2, ac, bc, 255);

  // layer 3+4: MFMA convT 256->128 in 4 chunks of 32 ch; conv4 accumulates
  for (int ch = 0; ch < 4; ++ch) {
    const int cb = ch * 32;
    convt_mfma<8, 256, 2, 2, 2, 32><<<dim3(1, 1024), 256, 0, stream>>>(y2, w3t, b3, y3c, cb);
    bnstats_kernel<<<dim3(1, 128), 256, 0, stream>>>(y3c, sp, sqp, 32, 32, 524288);
    bnfin_kernel<<<1, 256, 0, stream>>>(sp, sqp, g3 + cb, be3 + cb, ac, bc, 32, 1.0f / 524288.0f);
    bnact_kernel<<<8192, 256, 0, stream>>>(y3c, ac, bc, 31);
    conv4_kernel<<<2048, 256, 0, stream>>>(y3c, w4, b4, outp, cb, ch == 3);
  }
}

// Round 4
// 1575.527 us; speedup vs baseline: 2.5172x; 1.0002x over previous
//
#include <hip/hip_runtime.h>
#include <cstdint>
#include <cstddef>

// ----------------------------------------------------------------------------
// R3: MFMA bf16 convT pipeline, channels-last activations, fp32 BN math.
// Workspace (bytes), all aliases sequenced by stream order; max end 135,036,928
// (<= R2-proven 135,073,792):
//   y2   @ 0           64MB  [2048][64][256] bf16
//   y1   @ 67108864    32MB  [2048][16][512] bf16   (dead after conv2)
//   w3t  @ 67108864    1MB   [128][16][256]  bf16   (written after conv2)
//   y3c  @ 100663296   32MB  [2048][256][32] bf16   (written at conv3)
//   w1t  @ 100663296   16MB  [1000][16][512] bf16   (dead after conv1)
//   w2t  @ 117047296   4MB   [256][16][512]  bf16   (dead after conv2)
//   vals @ 134217728, idxs @ 134627328               (dead after conv1)
//   sp   @ 134217728, sqp @ 134479872, ac @ 134742016, bc @ 134744064
// ----------------------------------------------------------------------------

typedef unsigned short u16;
typedef unsigned int u32;
typedef __attribute__((ext_vector_type(8))) short s16x8;   // 8 bf16 (4 VGPR)
typedef __attribute__((ext_vector_type(4))) float f32x4;

static __device__ __forceinline__ float bf2f(u16 u) {
  union { u32 i; float f; } v; v.i = ((u32)u) << 16; return v.f;
}
static __device__ __forceinline__ u16 f2bf(float f) {  // RNE
  union { float f; u32 i; } v; v.f = f;
  const u32 r = v.i + 0x7fffu + ((v.i >> 16) & 1u);
  return (u16)(r >> 16);
}

// ---------------- top-k(50) + log/clamp/shift (unchanged, proven) -----------
__global__ __launch_bounds__(256) void topk_kernel(const float* __restrict__ x,
                                                   float* __restrict__ vals,
                                                   int* __restrict__ idxs) {
  const int b = blockIdx.x;
  const int t = threadIdx.x;
  __shared__ float sv[1024];
  __shared__ float redv[4];
  __shared__ int redi[4];
  __shared__ float tv[50];
  __shared__ int ti[50];
  __shared__ float sshift;
  for (int i = t; i < 1000; i += 256) sv[i] = x[(size_t)b * 1000 + i];
  for (int i = 1000 + t; i < 1024; i += 256) sv[i] = -INFINITY;
  __syncthreads();
  for (int k = 0; k < 50; ++k) {
    float bv = -INFINITY;
    int bi = 0x7fffffff;
    #pragma unroll
    for (int s = 0; s < 4; ++s) {
      const int i = t + s * 256;
      const float v = sv[i];
      if (v > bv) { bv = v; bi = i; }
    }
    for (int off = 32; off > 0; off >>= 1) {
      const float ov = __shfl_down(bv, off);
      const int oi = __shfl_down(bi, off);
      if (ov > bv || (ov == bv && oi < bi)) { bv = ov; bi = oi; }
    }
    if ((t & 63) == 0) { redv[t >> 6] = bv; redi[t >> 6] = bi; }
    __syncthreads();
    if (t == 0) {
      for (int w = 1; w < 4; ++w)
        if (redv[w] > bv || (redv[w] == bv && redi[w] < bi)) { bv = redv[w]; bi = redi[w]; }
      tv[k] = bv;
      ti[k] = bi;
      sv[bi] = -INFINITY;
    }
    __syncthreads();
  }
  if (t < 50) tv[t] = fmaxf(logf(tv[t]), -1000.0f) + 50.0f;
  __syncthreads();
  if (t == 0) {
    float mn = tv[0];
    for (int k = 1; k < 50; ++k) mn = fminf(mn, tv[k]);
    sshift = fmaxf(-mn, 0.0f);
  }
  __syncthreads();
  if (t < 50) {
    vals[b * 50 + t] = tv[t] + sshift;
    idxs[b * 50 + t] = ti[t];
  }
}

// ---------------- w1 transpose: [1000][512][16] f32 -> [1000][16][512] bf16 -
__global__ __launch_bounds__(256) void w1t_kernel(const float* __restrict__ w1,
                                                  u16* __restrict__ w1t) {
  const int cin = blockIdx.x;
  const int t = threadIdx.x;
  __shared__ float is[512 * 17];
  const float* src = w1 + (size_t)cin * 8192;
  #pragma unroll
  for (int r = 0; r < 8; ++r) {
    const int f = r * 1024 + t * 4;
    const float4 v = *reinterpret_cast<const float4*>(src + f);
    const int co = f >> 4, s = f & 15;   // s..s+3, same co
    is[co * 17 + s + 0] = v.x;
    is[co * 17 + s + 1] = v.y;
    is[co * 17 + s + 2] = v.z;
    is[co * 17 + s + 3] = v.w;
  }
  __syncthreads();
  u16* dst = w1t + (size_t)cin * 8192;
  #pragma unroll
  for (int p = 0; p < 4; ++p) {
    const int i8 = (p * 256 + t) * 8;    // flat = s*512 + co
    const int s = i8 >> 9, co = i8 & 511;
    union { u16 h[8]; s16x8 v; } pk;
    #pragma unroll
    for (int q = 0; q < 8; ++q) pk.h[q] = f2bf(is[(co + q) * 17 + s]);
    *reinterpret_cast<s16x8*>(dst + i8) = pk.v;
  }
}

// ---------------- w2/w3 transpose: [CIN][COUT][16] f32 -> [COUT][16][CIN] bf16
template <int CIN, int COUT>
__global__ __launch_bounds__(256) void wt_kernel(const float* __restrict__ w,
                                                 u16* __restrict__ wt) {
  const int o = blockIdx.x;
  const int t = threadIdx.x;
  __shared__ __align__(16) u16 tile[16 * CIN];
  for (int c = t; c < CIN; c += 256) {
    const float* src = w + ((size_t)c * COUT + o) * 16;
    #pragma unroll
    for (int q4 = 0; q4 < 4; ++q4) {
      const float4 v = *reinterpret_cast<const float4*>(src + q4 * 4);
      tile[(q4 * 4 + 0) * CIN + c] = f2bf(v.x);
      tile[(q4 * 4 + 1) * CIN + c] = f2bf(v.y);
      tile[(q4 * 4 + 2) * CIN + c] = f2bf(v.z);
      tile[(q4 * 4 + 3) * CIN + c] = f2bf(v.w);
    }
  }
  __syncthreads();
  u16* dst = wt + (size_t)o * 16 * CIN;
  for (int i8 = t * 8; i8 < 16 * CIN; i8 += 2048)
    *reinterpret_cast<s16x8*>(dst + i8) = *reinterpret_cast<const s16x8*>(tile + i8);
}

// ---------------- conv1: sparse gather, channels-last y1 [2048][16][512] ----
__global__ __launch_bounds__(256) void conv1_kernel(const float* __restrict__ vals,
                                                    const int* __restrict__ idxs,
                                                    const u16* __restrict__ w1t,
                                                    const float* __restrict__ b1,
                                                    u16* __restrict__ y1) {
  const int b = blockIdx.x;
  const int t = threadIdx.x;
  __shared__ float sval[50];
  __shared__ int sidx[50];
  if (t < 50) { sval[t] = vals[b * 50 + t]; sidx[t] = idxs[b * 50 + t]; }
  __syncthreads();
  const int co = (t & 63) * 8;
  const int s0 = t >> 6;
  float b8[8];
  #pragma unroll
  for (int q = 0; q < 8; ++q) b8[q] = b1[co + q];
  #pragma unroll
  for (int sp = 0; sp < 4; ++sp) {
    const int s = sp * 4 + s0;
    float acc[8] = {0.f, 0.f, 0.f, 0.f, 0.f, 0.f, 0.f, 0.f};
    for (int j = 0; j < 50; ++j) {
      const float v = sval[j];
      union { s16x8 v8; u16 h[8]; } w;
      w.v8 = *reinterpret_cast<const s16x8*>(w1t + (size_t)sidx[j] * 8192 + s * 512 + co);
      #pragma unroll
      for (int q = 0; q < 8; ++q) acc[q] = fmaf(v, bf2f(w.h[q]), acc[q]);
    }
    union { u16 h[8]; s16x8 v8; } o;
    #pragma unroll
    for (int q = 0; q < 8; ++q) o.h[q] = f2bf(acc[q] + b8[q]);
    *reinterpret_cast<s16x8*>(y1 + (size_t)b * 8192 + s * 512 + co) = o.v8;
  }
}

// ---------------- BN stats, channels-last [ROWS][C] (128 splits) ------------
__global__ __launch_bounds__(256) void bnstats_kernel(const u16* __restrict__ y,
                                                      float* __restrict__ sp,
                                                      float* __restrict__ sqp,
                                                      int C, int CB, int ROWS) {
  const int PB = CB >> 1;          // channel pairs per block
  const int PR = 256 / PB;         // row groups
  const int t = threadIdx.x;
  const int cp = t & (PB - 1);
  const int rl = t / PB;
  const int cbase = blockIdx.x * CB;
  const int split = blockIdx.y;
  const int RPB = ROWS >> 7;
  const u16* base = y + (size_t)split * RPB * C + cbase + 2 * cp;
  float s0 = 0.f, s1 = 0.f, q0 = 0.f, q1 = 0.f;
  for (int r = rl; r < RPB; r += PR) {
    const u32 raw = *reinterpret_cast<const u32*>(base + (size_t)r * C);
    const float a = bf2f((u16)(raw & 0xffffu));
    const float b = bf2f((u16)(raw >> 16));
    s0 += a; s1 += b;
    q0 = fmaf(a, a, q0); q1 = fmaf(b, b, q1);
  }
  __shared__ float4 arr[256];
  arr[t] = make_float4(s0, s1, q0, q1);
  __syncthreads();
  if (t < PB) {
    float4 acc = arr[t];
    for (int g = 1; g < PR; ++g) {
      const float4 v = arr[g * PB + t];
      acc.x += v.x; acc.y += v.y; acc.z += v.z; acc.w += v.w;
    }
    const int c = cbase + 2 * t;
    sp[split * C + c] = acc.x;
    sp[split * C + c + 1] = acc.y;
    sqp[split * C + c] = acc.z;
    sqp[split * C + c + 1] = acc.w;
  }
}

__global__ __launch_bounds__(256) void bnfin_kernel(const float* __restrict__ sp,
                                                    const float* __restrict__ sqp,
                                                    const float* __restrict__ g,
                                                    const float* __restrict__ be,
                                                    float* __restrict__ a,
                                                    float* __restrict__ bb,
                                                    int C, float inv) {
  const int c = blockIdx.x * 256 + threadIdx.x;
  if (c >= C) return;
  float s = 0.f, s2 = 0.f;
  for (int k = 0; k < 128; ++k) { s += sp[k * C + c]; s2 += sqp[k * C + c]; }
  const float m = s * inv;
  float var = fmaf(-m, m, s2 * inv);
  var = fmaxf(var, 0.f);
  const float r = 1.0f / sqrtf(var + 1e-5f);
  const float av = g[c] * r;
  a[c] = av;
  bb[c] = fmaf(-m, av, be[c]);
}

// ---------------- BN affine + tanh in place, channels-last ------------------
__global__ __launch_bounds__(256) void bnact_kernel(u16* __restrict__ y,
                                                    const float* __restrict__ a,
                                                    const float* __restrict__ bb,
                                                    int Cm1) {
  const size_t i = ((size_t)blockIdx.x * 256 + threadIdx.x) * 8;
  const int c = (int)i & Cm1;
  uint4 raw = *reinterpret_cast<uint4*>(y + i);
  float av[8], bv[8];
  *reinterpret_cast<float4*>(av) = *reinterpret_cast<const float4*>(a + c);
  *reinterpret_cast<float4*>(av + 4) = *reinterpret_cast<const float4*>(a + c + 4);
  *reinterpret_cast<float4*>(bv) = *reinterpret_cast<const float4*>(bb + c);
  *reinterpret_cast<float4*>(bv + 4) = *reinterpret_cast<const float4*>(bb + c + 4);
  u32 w[4] = {raw.x, raw.y, raw.z, raw.w};
  #pragma unroll
  for (int q = 0; q < 4; ++q) {
    const float lo = tanhf(fmaf(bf2f((u16)(w[q] & 0xffffu)), av[2 * q], bv[2 * q]));
    const float hi = tanhf(fmaf(bf2f((u16)(w[q] >> 16)), av[2 * q + 1], bv[2 * q + 1]));
    w[q] = (u32)f2bf(lo) | ((u32)f2bf(hi) << 16);
  }
  raw.x = w[0]; raw.y = w[1]; raw.z = w[2]; raw.w = w[3];
  *reinterpret_cast<uint4*>(y + i) = raw;
}

// ---------------- MFMA convT k=4 s=2 p=1 ------------------------------------
// in: [B][SIN*SIN][CIN] bf16 channels-last. wt: [COUT_W][16][CIN] bf16.
// out: [B][4*SIN*SIN][COUT_STORE] bf16, out channel slice [o_gbase, +NB*gridx).
// Per parity (py,px): out(2sy+py,2sx+px) = sum_j in(sy+DY[py][j], sx+DX..) * w[ky,kx]
__global__ void dummy_never(){}

template <int SIN, int CIN, int WM, int WN, int MBATCH, int COUT_STORE>
__global__ __launch_bounds__(256) void convt_mfma(const u16* __restrict__ in,
                                                  const u16* __restrict__ wt,
                                                  const float* __restrict__ bias,
                                                  u16* __restrict__ outp,
                                                  int o_gbase) {
  constexpr int SS = SIN * SIN;
  constexpr int MB = MBATCH * SS;          // input rows per block
  constexpr int MFR = MB / (16 * WM);      // m-frags per wave
  constexpr int NB = WN * 16;              // out channels per block
  constexpr int LOGS = (SIN == 4) ? 2 : 3;
  constexpr int KYT[2][2] = {{1, 3}, {2, 0}};
  constexpr int DYT[2][2] = {{0, -1}, {0, 1}};
  static_assert(MB % 32 == 0, "staging");
  __shared__ __align__(16) u16 As[(MB + 1) * 64];   // swizzled [MB+1][64]

  const int t = threadIdx.x;
  const int lane = t & 63;
  const int wave = t >> 6;
  const int wn = wave % WN;
  const int wm = wave / WN;
  const int l15 = lane & 15;
  const int kl = lane >> 4;
  const int bx = blockIdx.x;
  const int R0 = blockIdx.y * MB;

  // row-base addresses for the 9 shifts x MFR frags (swizzle pre-folded)
  int rb[9][MFR];
  #pragma unroll
  for (int m = 0; m < MFR; ++m) {
    const int r = wm * (MB / WM) + m * 16 + l15;
    const int bl = r >> (2 * LOGS);
    const int rr = r & (SS - 1);
    const int sy = rr >> LOGS, sx = rr & (SIN - 1);
    #pragma unroll
    for (int dyi = 0; dyi < 3; ++dyi)
      #pragma unroll
      for (int dxi = 0; dxi < 3; ++dxi) {
        const int ny = sy + dyi - 1, nx = sx + dxi - 1;
        const bool ok = (ny >= 0 && ny < SIN && nx >= 0 && nx < SIN);
        const int rp = ok ? ((bl << (2 * LOGS)) + (ny << LOGS) + nx) : MB;
        rb[dyi * 3 + dxi][m] = (rp << 7) | ((rp & 7) << 4);
      }
  }
  if (t < 8) { s16x8 z = {}; *reinterpret_cast<s16x8*>(As + MB * 64 + t * 8) = z; }

  f32x4 acc[2][2][MFR];
  #pragma unroll
  for (int py = 0; py < 2; ++py)
    #pragma unroll
    for (int px = 0; px < 2; ++px)
      #pragma unroll
      for (int m = 0; m < MFR; ++m) acc[py][px][m] = (f32x4){0.f, 0.f, 0.f, 0.f};

  const int ocol = o_gbase + bx * NB + wn * 16 + l15;   // absolute out channel
  const size_t wbase = (size_t)ocol * 16 * CIN + kl * 8;
  const int kl16 = kl * 16;

  for (int c0 = 0; c0 < CIN; c0 += 64) {
    __syncthreads();
    #pragma unroll
    for (int pass = 0; pass < MB / 32; ++pass) {
      const int row = pass * 32 + (t >> 3);
      const int co8 = (t & 7) * 8;
      const s16x8 v = *reinterpret_cast<const s16x8*>(
          in + (size_t)(R0 + row) * CIN + c0 + co8);
      const int db = row * 128 + ((co8 * 2) ^ ((row & 7) << 4));
      *reinterpret_cast<s16x8*>((char*)As + db) = v;
    }
    __syncthreads();
    #pragma unroll
    for (int kh = 0; kh < 2; ++kh) {
      const int koff = kh * 64 + kl16;
      const size_t kw = wbase + c0 + kh * 32;
      s16x8 bf[2][2][2][2];
      #pragma unroll
      for (int py = 0; py < 2; ++py)
        #pragma unroll
        for (int px = 0; px < 2; ++px)
          #pragma unroll
          for (int jy = 0; jy < 2; ++jy)
            #pragma unroll
            for (int jx = 0; jx < 2; ++jx) {
              const int tap = KYT[py][jy] * 4 + KYT[px][jx];
              bf[py][px][jy][jx] =
                  *reinterpret_cast<const s16x8*>(wt + kw + (size_t)tap * CIN);
            }
      #pragma unroll
      for (int m = 0; m < MFR; ++m) {
        s16x8 af[9];
        #pragma unroll
        for (int s9 = 0; s9 < 9; ++s9)
          af[s9] = *reinterpret_cast<const s16x8*>((char*)As + (rb[s9][m] ^ koff));
        #pragma unroll
        for (int py = 0; py < 2; ++py)
          #pragma unroll
          for (int px = 0; px < 2; ++px)
            #pragma unroll
            for (int jy = 0; jy < 2; ++jy)
              #pragma unroll
              for (int jx = 0; jx < 2; ++jx) {
                const int s9 = (DYT[py][jy] + 1) * 3 + (DYT[px][jx] + 1);
                acc[py][px][m] = __builtin_amdgcn_mfma_f32_16x16x32_bf16(
                    af[s9], bf[py][px][jy][jx], acc[py][px][m], 0, 0, 0);
              }
      }
    }
  }

  const int cstore = bx * NB + wn * 16 + l15;
  const float bo = bias[ocol];
  const int B0 = blockIdx.y * MBATCH;
  #pragma unroll
  for (int m = 0; m < MFR; ++m)
    #pragma unroll
    for (int i = 0; i < 4; ++i) {
      const int r = wm * (MB / WM) + m * 16 + kl * 4 + i;
      const int bl = r >> (2 * LOGS);
      const int rr = r & (SS - 1);
      const int sy = rr >> LOGS, sx = rr & (SIN - 1);
      const size_t ob = (size_t)(B0 + bl) * 4 * SS;
      #pragma unroll
      for (int py = 0; py < 2; ++py)
        #pragma unroll
        for (int px = 0; px < 2; ++px) {
          const int od = (2 * sy + py) * (2 * SIN) + 2 * sx + px;
          outp[(ob + od) * COUT_STORE + cstore] = f2bf(acc[py][px][m][i] + bo);
        }
    }
}

// ---------------- conv4: 32-ch slice of channels-last h3 -> accumulate out --
__global__ __launch_bounds__(256) void conv4_kernel(const u16* __restrict__ h3c,
                                                    const float* __restrict__ w4,
                                                    const float* __restrict__ b4,
                                                    float* __restrict__ outp,
                                                    int cbase, int last) {
  const int b = blockIdx.x;
  const int t = threadIdx.x;
  __shared__ float wsh[32 * 16];
  __shared__ float is[32 * 257];
  for (int i = t; i < 512; i += 256) wsh[i] = w4[cbase * 16 + i];
  #pragma unroll
  for (int p = 0; p < 4; ++p) {
    const int idx8 = p * 256 + t;
    const int s = idx8 >> 2;
    const int c0 = (idx8 & 3) * 8;
    union { s16x8 v8; u16 h[8]; } r;
    r.v8 = *reinterpret_cast<const s16x8*>(h3c + ((size_t)b * 256 + s) * 32 + c0);
    #pragma unroll
    for (int q = 0; q < 8; ++q) is[(c0 + q) * 257 + s] = bf2f(r.h[q]);
  }
  __syncthreads();
  float acc[4] = {0.f, 0.f, 0.f, 0.f};
  const int ox = t & 31;
  const int oy0 = t >> 5;
  for (int c = 0; c < 32; ++c) {
    #pragma unroll
    for (int k = 0; k < 4; ++k) {
      const int oy = oy0 + 8 * k;
      #pragma unroll
      for (int jy = 0; jy < 2; ++jy) {
        const int ky = 2 * jy + 1 - (oy & 1);
        const int iyn = oy + 1 - ky;
        if ((unsigned)iyn < 32u) {
          const int iy = iyn >> 1;
          #pragma unroll
          for (int jx = 0; jx < 2; ++jx) {
            const int kx = 2 * jx + 1 - (ox & 1);
            const int ixn = ox + 1 - kx;
            if ((unsigned)ixn < 32u) {
              const int ix = ixn >> 1;
              acc[k] = fmaf(is[c * 257 + iy * 16 + ix], wsh[c * 16 + ky * 4 + kx], acc[k]);
            }
          }
        }
      }
    }
  }
  #pragma unroll
  for (int k = 0; k < 4; ++k) {
    const int oy = oy0 + 8 * k;
    const size_t ob = (size_t)b * 1024 + oy * 32 + ox;
    const float base = (cbase == 0) ? b4[0] : outp[ob];
    const float v = base + acc[k];
    outp[ob] = last ? (1.0f / (1.0f + expf(-v))) : v;
  }
}

// ----------------------------------------------------------------------------
extern "C" void kernel_launch(void* const* d_in, const int* in_sizes, int n_in,
                              void* d_out, int out_size, void* d_ws, size_t ws_size,
                              hipStream_t stream) {
  (void)in_sizes; (void)n_in; (void)out_size; (void)ws_size;
  const float* x   = (const float*)d_in[0];
  const float* w1  = (const float*)d_in[1];
  const float* b1  = (const float*)d_in[2];
  const float* g1  = (const float*)d_in[3];
  const float* be1 = (const float*)d_in[4];
  const float* w2  = (const float*)d_in[5];
  const float* b2  = (const float*)d_in[6];
  const float* g2  = (const float*)d_in[7];
  const float* be2 = (const float*)d_in[8];
  const float* w3  = (const float*)d_in[9];
  const float* b3  = (const float*)d_in[10];
  const float* g3  = (const float*)d_in[11];
  const float* be3 = (const float*)d_in[12];
  const float* w4  = (const float*)d_in[13];
  const float* b4  = (const float*)d_in[14];

  char* ws = (char*)d_ws;
  u16*   y2   = (u16*)(ws + 0);
  u16*   y1   = (u16*)(ws + 67108864);
  u16*   w3t  = (u16*)(ws + 67108864);    // after conv2 (aliases y1)
  u16*   y3c  = (u16*)(ws + 100663296);
  u16*   w1t  = (u16*)(ws + 100663296);   // dead after conv1 (aliases y3c)
  u16*   w2t  = (u16*)(ws + 117047296);   // dead after conv2 (aliases y3c)
  float* vals = (float*)(ws + 134217728);
  int*   idxs = (int*)(ws + 134627328);
  float* sp   = (float*)(ws + 134217728); // after conv1 (aliases vals)
  float* sqp  = (float*)(ws + 134479872);
  float* ac   = (float*)(ws + 134742016);
  float* bc   = (float*)(ws + 134744064);
  float* outp = (float*)d_out;

  // precomputes + truncation vector
  w1t_kernel<<<1000, 256, 0, stream>>>(w1, w1t);
  wt_kernel<512, 256><<<256, 256, 0, stream>>>(w2, w2t);
  topk_kernel<<<2048, 256, 0, stream>>>(x, vals, idxs);

  // layer 1
  conv1_kernel<<<2048, 256, 0, stream>>>(vals, idxs, w1t, b1, y1);
  bnstats_kernel<<<dim3(4, 128), 256, 0, stream>>>(y1, sp, sqp, 512, 128, 32768);
  bnfin_kernel<<<2, 256, 0, stream>>>(sp, sqp, g1, be1, ac, bc, 512, 1.0f / 32768.0f);
  bnact_kernel<<<8192, 256, 0, stream>>>(y1, ac, bc, 511);

  // layer 2: MFMA convT 512->256, 4x4 -> 8x8
  convt_mfma<4, 512, 1, 4, 4, 256><<<dim3(4, 512), 256, 0, stream>>>(y1, w2t, b2, y2, 0);
  wt_kernel<256, 128><<<128, 256, 0, stream>>>(w3, w3t);
  bnstats_kernel<<<dim3(2, 128), 256, 0, stream>>>(y2, sp, sqp, 256, 128, 131072);
  bnfin_kernel<<<1, 256, 0, stream>>>(sp, sqp, g2, be2, ac, bc, 256, 1.0f / 131072.0f);
  bnact_kernel<<<16384, 256, 0, stream>>>(y2, ac, bc, 255);

  // layer 3+4: MFMA convT 256->128 in 4 chunks of 32 ch; conv4 accumulates
  for (int ch = 0; ch < 4; ++ch) {
    const int cb = ch * 32;
    convt_mfma<8, 256, 2, 2, 2, 32><<<dim3(1, 1024), 256, 0, stream>>>(y2, w3t, b3, y3c, cb);
    bnstats_kernel<<<dim3(1, 128), 256, 0, stream>>>(y3c, sp, sqp, 32, 32, 524288);
    bnfin_kernel<<<1, 256, 0, stream>>>(sp, sqp, g3 + cb, be3 + cb, ac, bc, 32, 1.0f / 524288.0f);
    bnact_kernel<<<8192, 256, 0, stream>>>(y3c, ac, bc, 31);
    conv4_kernel<<<2048, 256, 0, stream>>>(y3c, w4, b4, outp, cb, ch == 3);
  }
}

// Round 5
// 1575.331 us; speedup vs baseline: 2.5175x; 1.0001x over previous
//
#include <hip/hip_runtime.h>
#include <cstdint>
#include <cstddef>

// ----------------------------------------------------------------------------
// R3: MFMA bf16 convT pipeline, channels-last activations, fp32 BN math.
// Workspace (bytes), all aliases sequenced by stream order; max end 135,036,928
// (<= R2-proven 135,073,792):
//   y2   @ 0           64MB  [2048][64][256] bf16
//   y1   @ 67108864    32MB  [2048][16][512] bf16   (dead after conv2)
//   w3t  @ 67108864    1MB   [128][16][256]  bf16   (written after conv2)
//   y3c  @ 100663296   32MB  [2048][256][32] bf16   (written at conv3)
//   w1t  @ 100663296   16MB  [1000][16][512] bf16   (dead after conv1)
//   w2t  @ 117047296   4MB   [256][16][512]  bf16   (dead after conv2)
//   vals @ 134217728, idxs @ 134627328               (dead after conv1)
//   sp   @ 134217728, sqp @ 134479872, ac @ 134742016, bc @ 134744064
// ----------------------------------------------------------------------------

typedef unsigned short u16;
typedef unsigned int u32;
typedef __attribute__((ext_vector_type(8))) short s16x8;   // 8 bf16 (4 VGPR)
typedef __attribute__((ext_vector_type(4))) float f32x4;

static __device__ __forceinline__ float bf2f(u16 u) {
  union { u32 i; float f; } v; v.i = ((u32)u) << 16; return v.f;
}
static __device__ __forceinline__ u16 f2bf(float f) {  // RNE
  union { float f; u32 i; } v; v.f = f;
  const u32 r = v.i + 0x7fffu + ((v.i >> 16) & 1u);
  return (u16)(r >> 16);
}

// ---------------- top-k(50) + log/clamp/shift (unchanged, proven) -----------
__global__ __launch_bounds__(256) void topk_kernel(const float* __restrict__ x,
                                                   float* __restrict__ vals,
                                                   int* __restrict__ idxs) {
  const int b = blockIdx.x;
  const int t = threadIdx.x;
  __shared__ float sv[1024];
  __shared__ float redv[4];
  __shared__ int redi[4];
  __shared__ float tv[50];
  __shared__ int ti[50];
  __shared__ float sshift;
  for (int i = t; i < 1000; i += 256) sv[i] = x[(size_t)b * 1000 + i];
  for (int i = 1000 + t; i < 1024; i += 256) sv[i] = -INFINITY;
  __syncthreads();
  for (int k = 0; k < 50; ++k) {
    float bv = -INFINITY;
    int bi = 0x7fffffff;
    #pragma unroll
    for (int s = 0; s < 4; ++s) {
      const int i = t + s * 256;
      const float v = sv[i];
      if (v > bv) { bv = v; bi = i; }
    }
    for (int off = 32; off > 0; off >>= 1) {
      const float ov = __shfl_down(bv, off);
      const int oi = __shfl_down(bi, off);
      if (ov > bv || (ov == bv && oi < bi)) { bv = ov; bi = oi; }
    }
    if ((t & 63) == 0) { redv[t >> 6] = bv; redi[t >> 6] = bi; }
    __syncthreads();
    if (t == 0) {
      for (int w = 1; w < 4; ++w)
        if (redv[w] > bv || (redv[w] == bv && redi[w] < bi)) { bv = redv[w]; bi = redi[w]; }
      tv[k] = bv;
      ti[k] = bi;
      sv[bi] = -INFINITY;
    }
    __syncthreads();
  }
  if (t < 50) tv[t] = fmaxf(logf(tv[t]), -1000.0f) + 50.0f;
  __syncthreads();
  if (t == 0) {
    float mn = tv[0];
    for (int k = 1; k < 50; ++k) mn = fminf(mn, tv[k]);
    sshift = fmaxf(-mn, 0.0f);
  }
  __syncthreads();
  if (t < 50) {
    vals[b * 50 + t] = tv[t] + sshift;
    idxs[b * 50 + t] = ti[t];
  }
}

// ---------------- w1 transpose: [1000][512][16] f32 -> [1000][16][512] bf16 -
__global__ __launch_bounds__(256) void w1t_kernel(const float* __restrict__ w1,
                                                  u16* __restrict__ w1t) {
  const int cin = blockIdx.x;
  const int t = threadIdx.x;
  __shared__ float is[512 * 17];
  const float* src = w1 + (size_t)cin * 8192;
  #pragma unroll
  for (int r = 0; r < 8; ++r) {
    const int f = r * 1024 + t * 4;
    const float4 v = *reinterpret_cast<const float4*>(src + f);
    const int co = f >> 4, s = f & 15;   // s..s+3, same co
    is[co * 17 + s + 0] = v.x;
    is[co * 17 + s + 1] = v.y;
    is[co * 17 + s + 2] = v.z;
    is[co * 17 + s + 3] = v.w;
  }
  __syncthreads();
  u16* dst = w1t + (size_t)cin * 8192;
  #pragma unroll
  for (int p = 0; p < 4; ++p) {
    const int i8 = (p * 256 + t) * 8;    // flat = s*512 + co
    const int s = i8 >> 9, co = i8 & 511;
    union { u16 h[8]; s16x8 v; } pk;
    #pragma unroll
    for (int q = 0; q < 8; ++q) pk.h[q] = f2bf(is[(co + q) * 17 + s]);
    *reinterpret_cast<s16x8*>(dst + i8) = pk.v;
  }
}

// ---------------- w2/w3 transpose: [CIN][COUT][16] f32 -> [COUT][16][CIN] bf16
template <int CIN, int COUT>
__global__ __launch_bounds__(256) void wt_kernel(const float* __restrict__ w,
                                                 u16* __restrict__ wt) {
  const int o = blockIdx.x;
  const int t = threadIdx.x;
  __shared__ __align__(16) u16 tile[16 * CIN];
  for (int c = t; c < CIN; c += 256) {
    const float* src = w + ((size_t)c * COUT + o) * 16;
    #pragma unroll
    for (int q4 = 0; q4 < 4; ++q4) {
      const float4 v = *reinterpret_cast<const float4*>(src + q4 * 4);
      tile[(q4 * 4 + 0) * CIN + c] = f2bf(v.x);
      tile[(q4 * 4 + 1) * CIN + c] = f2bf(v.y);
      tile[(q4 * 4 + 2) * CIN + c] = f2bf(v.z);
      tile[(q4 * 4 + 3) * CIN + c] = f2bf(v.w);
    }
  }
  __syncthreads();
  u16* dst = wt + (size_t)o * 16 * CIN;
  for (int i8 = t * 8; i8 < 16 * CIN; i8 += 2048)
    *reinterpret_cast<s16x8*>(dst + i8) = *reinterpret_cast<const s16x8*>(tile + i8);
}

// ---------------- conv1: sparse gather, channels-last y1 [2048][16][512] ----
__global__ __launch_bounds__(256) void conv1_kernel(const float* __restrict__ vals,
                                                    const int* __restrict__ idxs,
                                                    const u16* __restrict__ w1t,
                                                    const float* __restrict__ b1,
                                                    u16* __restrict__ y1) {
  const int b = blockIdx.x;
  const int t = threadIdx.x;
  __shared__ float sval[50];
  __shared__ int sidx[50];
  if (t < 50) { sval[t] = vals[b * 50 + t]; sidx[t] = idxs[b * 50 + t]; }
  __syncthreads();
  const int co = (t & 63) * 8;
  const int s0 = t >> 6;
  float b8[8];
  #pragma unroll
  for (int q = 0; q < 8; ++q) b8[q] = b1[co + q];
  #pragma unroll
  for (int sp = 0; sp < 4; ++sp) {
    const int s = sp * 4 + s0;
    float acc[8] = {0.f, 0.f, 0.f, 0.f, 0.f, 0.f, 0.f, 0.f};
    for (int j = 0; j < 50; ++j) {
      const float v = sval[j];
      union { s16x8 v8; u16 h[8]; } w;
      w.v8 = *reinterpret_cast<const s16x8*>(w1t + (size_t)sidx[j] * 8192 + s * 512 + co);
      #pragma unroll
      for (int q = 0; q < 8; ++q) acc[q] = fmaf(v, bf2f(w.h[q]), acc[q]);
    }
    union { u16 h[8]; s16x8 v8; } o;
    #pragma unroll
    for (int q = 0; q < 8; ++q) o.h[q] = f2bf(acc[q] + b8[q]);
    *reinterpret_cast<s16x8*>(y1 + (size_t)b * 8192 + s * 512 + co) = o.v8;
  }
}

// ---------------- BN stats, channels-last [ROWS][C] (128 splits) ------------
__global__ __launch_bounds__(256) void bnstats_kernel(const u16* __restrict__ y,
                                                      float* __restrict__ sp,
                                                      float* __restrict__ sqp,
                                                      int C, int CB, int ROWS) {
  const int PB = CB >> 1;          // channel pairs per block
  const int PR = 256 / PB;         // row groups
  const int t = threadIdx.x;
  const int cp = t & (PB - 1);
  const int rl = t / PB;
  const int cbase = blockIdx.x * CB;
  const int split = blockIdx.y;
  const int RPB = ROWS >> 7;
  const u16* base = y + (size_t)split * RPB * C + cbase + 2 * cp;
  float s0 = 0.f, s1 = 0.f, q0 = 0.f, q1 = 0.f;
  for (int r = rl; r < RPB; r += PR) {
    const u32 raw = *reinterpret_cast<const u32*>(base + (size_t)r * C);
    const float a = bf2f((u16)(raw & 0xffffu));
    const float b = bf2f((u16)(raw >> 16));
    s0 += a; s1 += b;
    q0 = fmaf(a, a, q0); q1 = fmaf(b, b, q1);
  }
  __shared__ float4 arr[256];
  arr[t] = make_float4(s0, s1, q0, q1);
  __syncthreads();
  if (t < PB) {
    float4 acc = arr[t];
    for (int g = 1; g < PR; ++g) {
      const float4 v = arr[g * PB + t];
      acc.x += v.x; acc.y += v.y; acc.z += v.z; acc.w += v.w;
    }
    const int c = cbase + 2 * t;
    sp[split * C + c] = acc.x;
    sp[split * C + c + 1] = acc.y;
    sqp[split * C + c] = acc.z;
    sqp[split * C + c + 1] = acc.w;
  }
}

__global__ __launch_bounds__(256) void bnfin_kernel(const float* __restrict__ sp,
                                                    const float* __restrict__ sqp,
                                                    const float* __restrict__ g,
                                                    const float* __restrict__ be,
                                                    float* __restrict__ a,
                                                    float* __restrict__ bb,
                                                    int C, float inv) {
  const int c = blockIdx.x * 256 + threadIdx.x;
  if (c >= C) return;
  float s = 0.f, s2 = 0.f;
  for (int k = 0; k < 128; ++k) { s += sp[k * C + c]; s2 += sqp[k * C + c]; }
  const float m = s * inv;
  float var = fmaf(-m, m, s2 * inv);
  var = fmaxf(var, 0.f);
  const float r = 1.0f / sqrtf(var + 1e-5f);
  const float av = g[c] * r;
  a[c] = av;
  bb[c] = fmaf(-m, av, be[c]);
}

// ---------------- BN affine + tanh in place, channels-last ------------------
__global__ __launch_bounds__(256) void bnact_kernel(u16* __restrict__ y,
                                                    const float* __restrict__ a,
                                                    const float* __restrict__ bb,
                                                    int Cm1) {
  const size_t i = ((size_t)blockIdx.x * 256 + threadIdx.x) * 8;
  const int c = (int)i & Cm1;
  uint4 raw = *reinterpret_cast<uint4*>(y + i);
  float av[8], bv[8];
  *reinterpret_cast<float4*>(av) = *reinterpret_cast<const float4*>(a + c);
  *reinterpret_cast<float4*>(av + 4) = *reinterpret_cast<const float4*>(a + c + 4);
  *reinterpret_cast<float4*>(bv) = *reinterpret_cast<const float4*>(bb + c);
  *reinterpret_cast<float4*>(bv + 4) = *reinterpret_cast<const float4*>(bb + c + 4);
  u32 w[4] = {raw.x, raw.y, raw.z, raw.w};
  #pragma unroll
  for (int q = 0; q < 4; ++q) {
    const float lo = tanhf(fmaf(bf2f((u16)(w[q] & 0xffffu)), av[2 * q], bv[2 * q]));
    const float hi = tanhf(fmaf(bf2f((u16)(w[q] >> 16)), av[2 * q + 1], bv[2 * q + 1]));
    w[q] = (u32)f2bf(lo) | ((u32)f2bf(hi) << 16);
  }
  raw.x = w[0]; raw.y = w[1]; raw.z = w[2]; raw.w = w[3];
  *reinterpret_cast<uint4*>(y + i) = raw;
}

// ---------------- MFMA convT k=4 s=2 p=1 ------------------------------------
// in: [B][SIN*SIN][CIN] bf16 channels-last. wt: [COUT_W][16][CIN] bf16.
// out: [B][4*SIN*SIN][COUT_STORE] bf16, out channel slice [o_gbase, +NB*gridx).
// Per parity (py,px): out(2sy+py,2sx+px) = sum_j in(sy+DY[py][j], sx+DX..) * w[ky,kx]
__global__ void dummy_never(){}

template <int SIN, int CIN, int WM, int WN, int MBATCH, int COUT_STORE>
__global__ __launch_bounds__(256) void convt_mfma(const u16* __restrict__ in,
                                                  const u16* __restrict__ wt,
                                                  const float* __restrict__ bias,
                                                  u16* __restrict__ outp,
                                                  int o_gbase) {
  constexpr int SS = SIN * SIN;
  constexpr int MB = MBATCH * SS;          // input rows per block
  constexpr int MFR = MB / (16 * WM);      // m-frags per wave
  constexpr int NB = WN * 16;              // out channels per block
  constexpr int LOGS = (SIN == 4) ? 2 : 3;
  constexpr int KYT[2][2] = {{1, 3}, {2, 0}};
  constexpr int DYT[2][2] = {{0, -1}, {0, 1}};
  static_assert(MB % 32 == 0, "staging");
  __shared__ __align__(16) u16 As[(MB + 1) * 64];   // swizzled [MB+1][64]

  const int t = threadIdx.x;
  const int lane = t & 63;
  const int wave = t >> 6;
  const int wn = wave % WN;
  const int wm = wave / WN;
  const int l15 = lane & 15;
  const int kl = lane >> 4;
  const int bx = blockIdx.x;
  const int R0 = blockIdx.y * MB;

  // row-base addresses for the 9 shifts x MFR frags (swizzle pre-folded)
  int rb[9][MFR];
  #pragma unroll
  for (int m = 0; m < MFR; ++m) {
    const int r = wm * (MB / WM) + m * 16 + l15;
    const int bl = r >> (2 * LOGS);
    const int rr = r & (SS - 1);
    const int sy = rr >> LOGS, sx = rr & (SIN - 1);
    #pragma unroll
    for (int dyi = 0; dyi < 3; ++dyi)
      #pragma unroll
      for (int dxi = 0; dxi < 3; ++dxi) {
        const int ny = sy + dyi - 1, nx = sx + dxi - 1;
        const bool ok = (ny >= 0 && ny < SIN && nx >= 0 && nx < SIN);
        const int rp = ok ? ((bl << (2 * LOGS)) + (ny << LOGS) + nx) : MB;
        rb[dyi * 3 + dxi][m] = (rp << 7) | ((rp & 7) << 4);
      }
  }
  if (t < 8) { s16x8 z = {}; *reinterpret_cast<s16x8*>(As + MB * 64 + t * 8) = z; }

  f32x4 acc[2][2][MFR];
  #pragma unroll
  for (int py = 0; py < 2; ++py)
    #pragma unroll
    for (int px = 0; px < 2; ++px)
      #pragma unroll
      for (int m = 0; m < MFR; ++m) acc[py][px][m] = (f32x4){0.f, 0.f, 0.f, 0.f};

  const int ocol = o_gbase + bx * NB + wn * 16 + l15;   // absolute out channel
  const size_t wbase = (size_t)ocol * 16 * CIN + kl * 8;
  const int kl16 = kl * 16;

  for (int c0 = 0; c0 < CIN; c0 += 64) {
    __syncthreads();
    #pragma unroll
    for (int pass = 0; pass < MB / 32; ++pass) {
      const int row = pass * 32 + (t >> 3);
      const int co8 = (t & 7) * 8;
      const s16x8 v = *reinterpret_cast<const s16x8*>(
          in + (size_t)(R0 + row) * CIN + c0 + co8);
      const int db = row * 128 + ((co8 * 2) ^ ((row & 7) << 4));
      *reinterpret_cast<s16x8*>((char*)As + db) = v;
    }
    __syncthreads();
    #pragma unroll
    for (int kh = 0; kh < 2; ++kh) {
      const int koff = kh * 64 + kl16;
      const size_t kw = wbase + c0 + kh * 32;
      s16x8 bf[2][2][2][2];
      #pragma unroll
      for (int py = 0; py < 2; ++py)
        #pragma unroll
        for (int px = 0; px < 2; ++px)
          #pragma unroll
          for (int jy = 0; jy < 2; ++jy)
            #pragma unroll
            for (int jx = 0; jx < 2; ++jx) {
              const int tap = KYT[py][jy] * 4 + KYT[px][jx];
              bf[py][px][jy][jx] =
                  *reinterpret_cast<const s16x8*>(wt + kw + (size_t)tap * CIN);
            }
      #pragma unroll
      for (int m = 0; m < MFR; ++m) {
        s16x8 af[9];
        #pragma unroll
        for (int s9 = 0; s9 < 9; ++s9)
          af[s9] = *reinterpret_cast<const s16x8*>((char*)As + (rb[s9][m] ^ koff));
        #pragma unroll
        for (int py = 0; py < 2; ++py)
          #pragma unroll
          for (int px = 0; px < 2; ++px)
            #pragma unroll
            for (int jy = 0; jy < 2; ++jy)
              #pragma unroll
              for (int jx = 0; jx < 2; ++jx) {
                const int s9 = (DYT[py][jy] + 1) * 3 + (DYT[px][jx] + 1);
                acc[py][px][m] = __builtin_amdgcn_mfma_f32_16x16x32_bf16(
                    af[s9], bf[py][px][jy][jx], acc[py][px][m], 0, 0, 0);
              }
      }
    }
  }

  const int cstore = bx * NB + wn * 16 + l15;
  const float bo = bias[ocol];
  const int B0 = blockIdx.y * MBATCH;
  #pragma unroll
  for (int m = 0; m < MFR; ++m)
    #pragma unroll
    for (int i = 0; i < 4; ++i) {
      const int r = wm * (MB / WM) + m * 16 + kl * 4 + i;
      const int bl = r >> (2 * LOGS);
      const int rr = r & (SS - 1);
      const int sy = rr >> LOGS, sx = rr & (SIN - 1);
      const size_t ob = (size_t)(B0 + bl) * 4 * SS;
      #pragma unroll
      for (int py = 0; py < 2; ++py)
        #pragma unroll
        for (int px = 0; px < 2; ++px) {
          const int od = (2 * sy + py) * (2 * SIN) + 2 * sx + px;
          outp[(ob + od) * COUT_STORE + cstore] = f2bf(acc[py][px][m][i] + bo);
        }
    }
}

// ---------------- conv4: 32-ch slice of channels-last h3 -> accumulate out --
__global__ __launch_bounds__(256) void conv4_kernel(const u16* __restrict__ h3c,
                                                    const float* __restrict__ w4,
                                                    const float* __restrict__ b4,
                                                    float* __restrict__ outp,
                                                    int cbase, int last) {
  const int b = blockIdx.x;
  const int t = threadIdx.x;
  __shared__ float wsh[32 * 16];
  __shared__ float is[32 * 257];
  for (int i = t; i < 512; i += 256) wsh[i] = w4[cbase * 16 + i];
  #pragma unroll
  for (int p = 0; p < 4; ++p) {
    const int idx8 = p * 256 + t;
    const int s = idx8 >> 2;
    const int c0 = (idx8 & 3) * 8;
    union { s16x8 v8; u16 h[8]; } r;
    r.v8 = *reinterpret_cast<const s16x8*>(h3c + ((size_t)b * 256 + s) * 32 + c0);
    #pragma unroll
    for (int q = 0; q < 8; ++q) is[(c0 + q) * 257 + s] = bf2f(r.h[q]);
  }
  __syncthreads();
  float acc[4] = {0.f, 0.f, 0.f, 0.f};
  const int ox = t & 31;
  const int oy0 = t >> 5;
  for (int c = 0; c < 32; ++c) {
    #pragma unroll
    for (int k = 0; k < 4; ++k) {
      const int oy = oy0 + 8 * k;
      #pragma unroll
      for (int jy = 0; jy < 2; ++jy) {
        const int ky = 2 * jy + 1 - (oy & 1);
        const int iyn = oy + 1 - ky;
        if ((unsigned)iyn < 32u) {
          const int iy = iyn >> 1;
          #pragma unroll
          for (int jx = 0; jx < 2; ++jx) {
            const int kx = 2 * jx + 1 - (ox & 1);
            const int ixn = ox + 1 - kx;
            if ((unsigned)ixn < 32u) {
              const int ix = ixn >> 1;
              acc[k] = fmaf(is[c * 257 + iy * 16 + ix], wsh[c * 16 + ky * 4 + kx], acc[k]);
            }
          }
        }
      }
    }
  }
  #pragma unroll
  for (int k = 0; k < 4; ++k) {
    const int oy = oy0 + 8 * k;
    const size_t ob = (size_t)b * 1024 + oy * 32 + ox;
    const float base = (cbase == 0) ? b4[0] : outp[ob];
    const float v = base + acc[k];
    outp[ob] = last ? (1.0f / (1.0f + expf(-v))) : v;
  }
}

// ----------------------------------------------------------------------------
extern "C" void kernel_launch(void* const* d_in, const int* in_sizes, int n_in,
                              void* d_out, int out_size, void* d_ws, size_t ws_size,
                              hipStream_t stream) {
  (void)in_sizes; (void)n_in; (void)out_size; (void)ws_size;
  const float* x   = (const float*)d_in[0];
  const float* w1  = (const float*)d_in[1];
  const float* b1  = (const float*)d_in[2];
  const float* g1  = (const float*)d_in[3];
  const float* be1 = (const float*)d_in[4];
  const float* w2  = (const float*)d_in[5];
  const float* b2  = (const float*)d_in[6];
  const float* g2  = (const float*)d_in[7];
  const float* be2 = (const float*)d_in[8];
  const float* w3  = (const float*)d_in[9];
  const float* b3  = (const float*)d_in[10];
  const float* g3  = (const float*)d_in[11];
  const float* be3 = (const float*)d_in[12];
  const float* w4  = (const float*)d_in[13];
  const float* b4  = (const float*)d_in[14];

  char* ws = (char*)d_ws;
  u16*   y2   = (u16*)(ws + 0);
  u16*   y1   = (u16*)(ws + 67108864);
  u16*   w3t  = (u16*)(ws + 67108864);    // after conv2 (aliases y1)
  u16*   y3c  = (u16*)(ws + 100663296);
  u16*   w1t  = (u16*)(ws + 100663296);   // dead after conv1 (aliases y3c)
  u16*   w2t  = (u16*)(ws + 117047296);   // dead after conv2 (aliases y3c)
  float* vals = (float*)(ws + 134217728);
  int*   idxs = (int*)(ws + 134627328);
  float* sp   = (float*)(ws + 134217728); // after conv1 (aliases vals)
  float* sqp  = (float*)(ws + 134479872);
  float* ac   = (float*)(ws + 134742016);
  float* bc   = (float*)(ws + 134744064);
  float* outp = (float*)d_out;

  // precomputes + truncation vector
  w1t_kernel<<<1000, 256, 0, stream>>>(w1, w1t);
  wt_kernel<512, 256><<<256, 256, 0, stream>>>(w2, w2t);
  topk_kernel<<<2048, 256, 0, stream>>>(x, vals, idxs);

  // layer 1
  conv1_kernel<<<2048, 256, 0, stream>>>(vals, idxs, w1t, b1, y1);
  bnstats_kernel<<<dim3(4, 128), 256, 0, stream>>>(y1, sp, sqp, 512, 128, 32768);
  bnfin_kernel<<<2, 256, 0, stream>>>(sp, sqp, g1, be1, ac, bc, 512, 1.0f / 32768.0f);
  bnact_kernel<<<8192, 256, 0, stream>>>(y1, ac, bc, 511);

  // layer 2: MFMA convT 512->256, 4x4 -> 8x8
  convt_mfma<4, 512, 1, 4, 4, 256><<<dim3(4, 512), 256, 0, stream>>>(y1, w2t, b2, y2, 0);
  wt_kernel<256, 128><<<128, 256, 0, stream>>>(w3, w3t);
  bnstats_kernel<<<dim3(2, 128), 256, 0, stream>>>(y2, sp, sqp, 256, 128, 131072);
  bnfin_kernel<<<1, 256, 0, stream>>>(sp, sqp, g2, be2, ac, bc, 256, 1.0f / 131072.0f);
  bnact_kernel<<<16384, 256, 0, stream>>>(y2, ac, bc, 255);

  // layer 3+4: MFMA convT 256->128 in 4 chunks of 32 ch; conv4 accumulates
  for (int ch = 0; ch < 4; ++ch) {
    const int cb = ch * 32;
    convt_mfma<8, 256, 2, 2, 2, 32><<<dim3(1, 1024), 256, 0, stream>>>(y2, w3t, b3, y3c, cb);
    bnstats_kernel<<<dim3(1, 128), 256, 0, stream>>>(y3c, sp, sqp, 32, 32, 524288);
    bnfin_kernel<<<1, 256, 0, stream>>>(sp, sqp, g3 + cb, be3 + cb, ac, bc, 32, 1.0f / 524288.0f);
    bnact_kernel<<<8192, 256, 0, stream>>>(y3c, ac, bc, 31);
    conv4_kernel<<<2048, 256, 0, stream>>>(y3c, w4, b4, outp, cb, ch == 3);
  }
}